// Round 1
// baseline (844.050 us; speedup 1.0000x reference)
//
#include <hip/hip_runtime.h>

#define S_LEN 2048
#define BATCH 1024
#define HID 4
#define NL 6

__device__ __forceinline__ float fexp2(float x) { return __builtin_amdgcn_exp2f(x); }
__device__ __forceinline__ float frcp(float x)  { return __builtin_amdgcn_rcpf(x); }

// quad-perm broadcast of lane (quad_base + k) via ds_swizzle (pull semantics:
// dst[l] = src[(l & ~3) | p[l&3]], p[i] = k for all i)
template <int k>
__device__ __forceinline__ float qbcast(float v) {
    return __int_as_float(
        __builtin_amdgcn_ds_swizzle(__float_as_int(v), 0x8000 | (0x55 * k)));
}

// Block = 6 waves (one per layer), pipelined with skew: wave l processes
// timestep t = n - l at global step n. h handoff via double-buffered LDS,
// one __syncthreads per step. 4 batch elements per block (16 lanes each).
__global__ __launch_bounds__(384, 1) void lstm_pipe(
    const float* __restrict__ x, const float* __restrict__ w_ih,
    const float* __restrict__ w_hh, const float* __restrict__ b_ih,
    const float* __restrict__ b_hh, const float* __restrict__ reg_w,
    const float* __restrict__ reg_b, float* __restrict__ out) {
    const int tid  = threadIdx.x;
    const int l    = tid >> 6;        // wave index == layer
    const int lane = tid & 63;
    const int e    = lane >> 4;       // batch element within block (0..3)
    const int j    = (lane >> 2) & 3; // hidden unit
    const int g    = lane & 3;        // gate role: 0=i,1=f,2=g(cell),3=o
    const int b    = blockIdx.x * 4 + e;

    __shared__ __align__(16) float hbuf[2][NL][4][HID];

    // ---- per-lane preload ----
    const int r = g * HID + j;                 // row in [4H, H] weight matrix
    const float* wih = w_ih + (l * 16 + r) * HID;
    const float* whh = w_hh + (l * 16 + r) * HID;
    const float Wx0 = wih[0], Wx1 = wih[1], Wx2 = wih[2], Wx3 = wih[3];
    // recurrent weights permuted to match shfl_xor gather order (hv[m] = h[j^m])
    const float Wh0 = whh[j ^ 0], Wh1 = whh[j ^ 1], Wh2 = whh[j ^ 2], Wh3 = whh[j ^ 3];
    const float bias = b_ih[l * 16 + r] + b_hh[l * 16 + r];

    // activation constants: sigmoid for i/f/o, tanh (=2*sigmoid(2x)-1) for g
    const bool  is_g = (g == 2);
    const float cexp = is_g ? -2.885390082f : -1.442695041f; // -2*log2e : -log2e
    const float aact = is_g ? 2.0f : 1.0f;
    const float bact = is_g ? -1.0f : 0.0f;

    const float regw = reg_w[j];
    const float regb = reg_b[0];

    float h = 0.0f, c = 0.0f;

    // ---- x prefetch ring (used by wave 0 only) ----
    float4 xbuf[8];
    const float4* xp = (const float4*)x + b; // + t*BATCH per timestep
    if (l == 0) {
#pragma unroll
        for (int u = 0; u < 8; ++u) xbuf[u] = xp[(size_t)u * BATCH];
    }

    // global steps n = 0 .. 2055 (need up to 2052 for l=5; extras are idle)
    for (int m = 0; m < S_LEN + 8; m += 8) {
#pragma unroll
        for (int u = 0; u < 8; ++u) {
            const int n = m + u;
            const int t = n - l;
            const int p = n & 1;
            if (t >= 0 && t < S_LEN) { // wave-uniform guard
                // ---- layer input (natural order) ----
                float x0, x1, x2, x3;
                if (l == 0) {
                    float4 xv = xbuf[u];
                    x0 = xv.x; x1 = xv.y; x2 = xv.z; x3 = xv.w;
                    if (t + 8 < S_LEN) xbuf[u] = xp[(size_t)(t + 8) * BATCH];
                } else {
                    float4 xv = *(const float4*)&hbuf[p][l - 1][e][0];
                    x0 = xv.x; x1 = xv.y; x2 = xv.z; x3 = xv.w;
                }
                // ---- allgather own-layer h across units (xor-permuted) ----
                const float hv1 = __shfl_xor(h, 4);
                const float hv2 = __shfl_xor(h, 8);
                const float hv3 = __shfl_xor(h, 12);
                // ---- gate pre-activation: one gate per lane ----
                float G = bias;
                G = fmaf(Wx0, x0, G); G = fmaf(Wx1, x1, G);
                G = fmaf(Wx2, x2, G); G = fmaf(Wx3, x3, G);
                G = fmaf(Wh0, h, G);  G = fmaf(Wh1, hv1, G);
                G = fmaf(Wh2, hv2, G); G = fmaf(Wh3, hv3, G);
                // ---- activation (uniform stream, role via constants) ----
                const float ea  = fexp2(G * cexp);
                const float act = fmaf(aact, frcp(1.0f + ea), bact);
                // ---- gather all 4 gate activations within the quad ----
                const float si = qbcast<0>(act);
                const float sf = qbcast<1>(act);
                const float tg = qbcast<2>(act);
                const float so = qbcast<3>(act);
                // ---- cell update ----
                c = fmaf(sf, c, si * tg);
                const float ec = fexp2(c * -2.885390082f);
                const float tc = fmaf(2.0f, frcp(1.0f + ec), -1.0f);
                h = so * tc;
                // ---- publish h for next layer ----
                if (g == 0) hbuf[p ^ 1][l][e][j] = h;
                // ---- linear head (last layer) ----
                if (l == NL - 1) {
                    float s = h * regw;
                    s += __shfl_xor(s, 4);
                    s += __shfl_xor(s, 8);
                    if ((lane & 15) == 0) out[(size_t)t * BATCH + b] = s + regb;
                }
            }
            __syncthreads();
        }
    }
}

extern "C" void kernel_launch(void* const* d_in, const int* in_sizes, int n_in,
                              void* d_out, int out_size, void* d_ws, size_t ws_size,
                              hipStream_t stream) {
    const float* x     = (const float*)d_in[0];
    const float* w_ih  = (const float*)d_in[1];
    const float* w_hh  = (const float*)d_in[2];
    const float* b_ih  = (const float*)d_in[3];
    const float* b_hh  = (const float*)d_in[4];
    const float* reg_w = (const float*)d_in[5];
    const float* reg_b = (const float*)d_in[6];
    float* out = (float*)d_out;

    dim3 grid(BATCH / 4);
    dim3 block(384);
    hipLaunchKernelGGL(lstm_pipe, grid, block, 0, stream, x, w_ih, w_hh, b_ih,
                       b_hh, reg_w, reg_b, out);
}

// Round 2
// 581.996 us; speedup vs baseline: 1.4503x; 1.4503x over previous
//
#include <hip/hip_runtime.h>

#define S_LEN 2048
#define BATCH 1024
#define HID 4
#define NL 6
#define K 16                 // timesteps per chunk (one barrier per chunk)
#define EPB 8                // batch elements per block
#define NCH (S_LEN / K)      // 128 chunks
#define NSS (NCH + NL - 1)   // 133 super-steps

__device__ __forceinline__ float fexp2(float x) { return __builtin_amdgcn_exp2f(x); }
__device__ __forceinline__ float frcp(float x)  { return __builtin_amdgcn_rcpf(x); }

// DPP quad_perm broadcast/permute within a quad: dst[k] = src[quad | perm[k]]
// ctrl = p0 | p1<<2 | p2<<4 | p3<<6. xor1=[1,0,3,2]=0xB1, xor2=[2,3,0,1]=0x4E,
// xor3=[3,2,1,0]=0x1B.
template <int CTRL>
__device__ __forceinline__ float dppf(float v) {
    return __int_as_float(__builtin_amdgcn_update_dpp(
        0, __float_as_int(v), CTRL, 0xF, 0xF, true));
}

__device__ __forceinline__ float sigf(float x) {
    return frcp(1.0f + fexp2(x * -1.442695041f));          // sigmoid
}
__device__ __forceinline__ float tanh_(float x) {
    return fmaf(2.0f, frcp(1.0f + fexp2(x * -2.885390082f)), -1.0f);
}

// Block = 3 waves = 192 threads. Wave w carries layers 2w (lanes 0-31) and
// 2w+1 (lanes 32-63). Within a half-wave: 8 elements x 4 hidden-unit lanes;
// the 4 j-lanes of an element sit in one DPP quad. Each lane computes all 4
// gates of its unit (no gate gather); h allgather = 3 DPP quad_perms.
// Chunked software pipeline: at super-step s, layer L processes chunk q=s-L
// (16 timesteps) fully in registers; h handoff via double-buffered LDS with
// ONE __syncthreads per super-step.
__global__ __launch_bounds__(192, 1) void lstm_pipe2(
    const float* __restrict__ x, const float* __restrict__ w_ih,
    const float* __restrict__ w_hh, const float* __restrict__ b_ih,
    const float* __restrict__ b_hh, const float* __restrict__ reg_w,
    const float* __restrict__ reg_b, float* __restrict__ out) {
    const int tid  = threadIdx.x;
    const int w    = tid >> 6;
    const int lane = tid & 63;
    const int half = lane >> 5;
    const int L    = 2 * w + half;       // layer handled by this half-wave
    const int e    = (lane >> 2) & 7;    // element within block
    const int j    = lane & 3;           // hidden unit (quad position)
    const int b    = blockIdx.x * EPB + e;

    __shared__ __align__(16) float hbuf[2][NL - 1][K][EPB][HID];

    // ---- per-lane weight preload: all 4 gates of unit j, layer L ----
    float Wih[4][4], Whh[4][4], Gb[4];
#pragma unroll
    for (int g = 0; g < 4; ++g) {
        const int row = g * HID + j;
        const float* ih = w_ih + (L * 16 + row) * HID;
        const float* hh = w_hh + (L * 16 + row) * HID;
#pragma unroll
        for (int k = 0; k < 4; ++k) Wih[g][k] = ih[k];
        // permuted so that term m multiplies hv_m = h_{j^m}
#pragma unroll
        for (int m = 0; m < 4; ++m) Whh[g][m] = hh[j ^ m];
        Gb[g] = b_ih[L * 16 + row] + b_hh[L * 16 + row];
    }
    const float regw = reg_w[j];
    const float regb = reg_b[0];
    const bool  is_l0   = (L == 0);
    const bool  is_last = (L == NL - 1);

    float h = 0.0f, c = 0.0f;
    float4 Gp[K];    // gate pre-activations (bias + W_ih*x), one float4 per u
    float4 xreg[K];  // layer-0 input prefetch (chunk ahead)

    const float4* xp = (const float4*)x + b;
    if (is_l0) {
#pragma unroll
        for (int u = 0; u < K; ++u) xreg[u] = xp[(size_t)u * BATCH];
    }

    for (int s = 0; s < NSS; ++s) {
        const int  q      = s - L;
        const bool active = (q >= 0) && (q < NCH);
        const int  rp     = s & 1;      // read parity; write parity = rp^1

        // ---- chunk preamble: input projection for all 16 timesteps ----
        if (active) {
#pragma unroll
            for (int u = 0; u < K; ++u) {
                float4 xv;
                if (is_l0) {
                    xv = xreg[u];
                } else {
                    xv = *(const float4*)&hbuf[rp][L - 1][u][e][0];
                }
                float4 g4;
                g4.x = Gb[0]; g4.y = Gb[1]; g4.z = Gb[2]; g4.w = Gb[3];
                g4.x = fmaf(Wih[0][0], xv.x, g4.x); g4.x = fmaf(Wih[0][1], xv.y, g4.x);
                g4.x = fmaf(Wih[0][2], xv.z, g4.x); g4.x = fmaf(Wih[0][3], xv.w, g4.x);
                g4.y = fmaf(Wih[1][0], xv.x, g4.y); g4.y = fmaf(Wih[1][1], xv.y, g4.y);
                g4.y = fmaf(Wih[1][2], xv.z, g4.y); g4.y = fmaf(Wih[1][3], xv.w, g4.y);
                g4.z = fmaf(Wih[2][0], xv.x, g4.z); g4.z = fmaf(Wih[2][1], xv.y, g4.z);
                g4.z = fmaf(Wih[2][2], xv.z, g4.z); g4.z = fmaf(Wih[2][3], xv.w, g4.z);
                g4.w = fmaf(Wih[3][0], xv.x, g4.w); g4.w = fmaf(Wih[3][1], xv.y, g4.w);
                g4.w = fmaf(Wih[3][2], xv.z, g4.w); g4.w = fmaf(Wih[3][3], xv.w, g4.w);
                Gp[u] = g4;
            }
        }
        // ---- prefetch next chunk's x (layer 0); lands during inner loop ----
        if (is_l0 && (s + 1 < NCH)) {
#pragma unroll
            for (int u = 0; u < K; ++u)
                xreg[u] = xp[(size_t)((s + 1) * K + u) * BATCH];
        }
        // ---- recurrent inner loop: 16 steps, registers + DPP only ----
        if (active) {
#pragma unroll
            for (int u = 0; u < K; ++u) {
                const float hv1 = dppf<0xB1>(h);
                const float hv2 = dppf<0x4E>(h);
                const float hv3 = dppf<0x1B>(h);
                float Gi = Gp[u].x, Gf = Gp[u].y, Gg = Gp[u].z, Go = Gp[u].w;
                Gi = fmaf(Whh[0][0], h, Gi); Gi = fmaf(Whh[0][1], hv1, Gi);
                Gi = fmaf(Whh[0][2], hv2, Gi); Gi = fmaf(Whh[0][3], hv3, Gi);
                Gf = fmaf(Whh[1][0], h, Gf); Gf = fmaf(Whh[1][1], hv1, Gf);
                Gf = fmaf(Whh[1][2], hv2, Gf); Gf = fmaf(Whh[1][3], hv3, Gf);
                Gg = fmaf(Whh[2][0], h, Gg); Gg = fmaf(Whh[2][1], hv1, Gg);
                Gg = fmaf(Whh[2][2], hv2, Gg); Gg = fmaf(Whh[2][3], hv3, Gg);
                Go = fmaf(Whh[3][0], h, Go); Go = fmaf(Whh[3][1], hv1, Go);
                Go = fmaf(Whh[3][2], hv2, Go); Go = fmaf(Whh[3][3], hv3, Go);
                const float si = sigf(Gi);
                const float sf = sigf(Gf);
                const float tg = tanh_(Gg);
                const float so = sigf(Go);
                c = fmaf(sf, c, si * tg);
                h = so * tanh_(c);
                if (!is_last) {
                    hbuf[rp ^ 1][L][u][e][j] = h;
                } else {
                    float sum = h * regw;
                    sum += dppf<0xB1>(sum);
                    sum += dppf<0x4E>(sum);
                    if (j == 0) out[(size_t)(q * K + u) * BATCH + b] = sum + regb;
                }
            }
        }
        __syncthreads();
    }
}

extern "C" void kernel_launch(void* const* d_in, const int* in_sizes, int n_in,
                              void* d_out, int out_size, void* d_ws, size_t ws_size,
                              hipStream_t stream) {
    const float* x     = (const float*)d_in[0];
    const float* w_ih  = (const float*)d_in[1];
    const float* w_hh  = (const float*)d_in[2];
    const float* b_ih  = (const float*)d_in[3];
    const float* b_hh  = (const float*)d_in[4];
    const float* reg_w = (const float*)d_in[5];
    const float* reg_b = (const float*)d_in[6];
    float* out = (float*)d_out;

    dim3 grid(BATCH / EPB);   // 128 blocks: spread to 1 wave/SIMD chip-wide
    dim3 block(192);          // 3 waves: layers (0,1),(2,3),(4,5) per wave
    hipLaunchKernelGGL(lstm_pipe2, grid, block, 0, stream, x, w_ih, w_hh, b_ih,
                       b_hh, reg_w, reg_b, out);
}

// Round 3
// 507.788 us; speedup vs baseline: 1.6622x; 1.1461x over previous
//
#include <hip/hip_runtime.h>

#define S_LEN  2048
#define BATCH  1024
#define NL     6
#define CH     16      // timesteps per chunk (x-prefetch granularity)
#define NCHUNK 129     // 129*16 = 2064 >= 2048 + NL - 1 = 2053 steps

__device__ __forceinline__ float fexp2(float x) { return __builtin_amdgcn_exp2f(x); }
__device__ __forceinline__ float frcp(float x)  { return __builtin_amdgcn_rcpf(x); }

// quad_perm DPP: xor1=[1,0,3,2]=0xB1, xor2=[2,3,0,1]=0x4E, xor3=[3,2,1,0]=0x1B
template <int CTRL>
__device__ __forceinline__ float dppf(float v) {
    return __int_as_float(__builtin_amdgcn_update_dpp(
        0, __float_as_int(v), CTRL, 0xF, 0xF, true));
}
__device__ __forceinline__ float bpermf(int addr, float v) {
    return __int_as_float(__builtin_amdgcn_ds_bpermute(addr, __float_as_int(v)));
}
__device__ __forceinline__ float sigf(float x)  { return frcp(1.0f + fexp2(x * -1.442695041f)); }
__device__ __forceinline__ float tanh_(float x) { return fmaf(2.0f, frcp(1.0f + fexp2(x * -2.885390082f)), -1.0f); }

// ONE wave carries the whole 6-layer pipeline for 2 batch elements.
// lane = L*8 + e*4 + j (L=layer 0..5, e=element, j=hidden unit; lanes 48-55
// idle, lanes 56-63 are "feeder" lanes whose h register holds x[t,b,j]).
// Layer skew: at step n, layer L computes t = n - L. Handoff h_{L-1}->L is a
// single ds_bpermute (src = lane-8; L0 pulls from the feeders at lane+56).
// No __syncthreads, no LDS buffers, no cross-wave traffic of any kind.
__global__ __launch_bounds__(64, 1) void lstm_wavepipe(
    const float* __restrict__ x, const float* __restrict__ w_ih,
    const float* __restrict__ w_hh, const float* __restrict__ b_ih,
    const float* __restrict__ b_hh, const float* __restrict__ reg_w,
    const float* __restrict__ reg_b, float* __restrict__ out) {
    const int lane = threadIdx.x;
    const int L    = lane >> 3;
    const int e    = (lane >> 2) & 1;
    const int j    = lane & 3;
    const int b    = blockIdx.x * 2 + e;
    const int Lc   = (L < NL) ? L : NL - 1;      // clamp for safe weight loads
    const bool isFeeder = (lane >= 56);
    const bool isOut    = (L == 5) && (j == 0);

    // ---- weight preload, permuted so term m multiplies value of unit j^m ----
    float Wx[4][4], Wh[4][4], Gb[4];
#pragma unroll
    for (int g = 0; g < 4; ++g) {
        const int row = Lc * 16 + g * 4 + j;     // PyTorch gate order i,f,g,o
#pragma unroll
        for (int m = 0; m < 4; ++m) {
            Wx[g][m] = w_ih[row * 4 + (j ^ m)];
            Wh[g][m] = w_hh[row * 4 + (j ^ m)];
        }
        Gb[g] = b_ih[row] + b_hh[row];
    }
    const float regw = reg_w[j];
    const float regb = reg_b[0];
    const int bpaddr = ((lane >= 8) ? (lane - 8) : (lane + 56)) << 2;
    // step counter: after ++ at step n, tc = n - L; inactive lanes stay huge
    int tc = (L < NL) ? (-L - 1) : -2100000000;

    float h = 0.0f, c = 0.0f;
    float xu[CH], xp[CH], su[CH];
    const size_t xoff = (size_t)(b * 4 + j);     // x[t*4096 + 4b + j]

#pragma unroll
    for (int u = 0; u < CH; ++u) xu[u] = x[(size_t)u * 4096 + xoff];

    for (int cc = 0; cc < NCHUNK; ++cc) {
        // ---- prefetch next chunk's x (lands during the 16 steps below) ----
#pragma unroll
        for (int u = 0; u < CH; ++u) {
            int t2 = (cc + 1) * CH + u;
            if (t2 > S_LEN - 1) t2 = S_LEN - 1;
            xp[u] = x[(size_t)t2 * 4096 + xoff];
        }
        // ---- 16 pipeline steps: registers + 1 bpermute + 8 DPP per step ----
#pragma unroll
        for (int u = 0; u < CH; ++u) {
            ++tc;
            h = isFeeder ? xu[u] : h;            // feeders publish x[n]
            const float hup = bpermf(bpaddr, h); // h from layer above (or x)
            const float hv1 = dppf<0xB1>(h),   hv2 = dppf<0x4E>(h),   hv3 = dppf<0x1B>(h);
            const float xv1 = dppf<0xB1>(hup), xv2 = dppf<0x4E>(hup), xv3 = dppf<0x1B>(hup);
            float Gi = Gb[0], Gf = Gb[1], Gg = Gb[2], Go = Gb[3];
            // own-h terms first (independent of bpermute -> hides lgkm latency)
            Gi = fmaf(Wh[0][0], h, Gi);   Gf = fmaf(Wh[1][0], h, Gf);
            Gg = fmaf(Wh[2][0], h, Gg);   Go = fmaf(Wh[3][0], h, Go);
            Gi = fmaf(Wh[0][1], hv1, Gi); Gf = fmaf(Wh[1][1], hv1, Gf);
            Gg = fmaf(Wh[2][1], hv1, Gg); Go = fmaf(Wh[3][1], hv1, Go);
            Gi = fmaf(Wh[0][2], hv2, Gi); Gf = fmaf(Wh[1][2], hv2, Gf);
            Gg = fmaf(Wh[2][2], hv2, Gg); Go = fmaf(Wh[3][2], hv2, Go);
            Gi = fmaf(Wh[0][3], hv3, Gi); Gf = fmaf(Wh[1][3], hv3, Gf);
            Gg = fmaf(Wh[2][3], hv3, Gg); Go = fmaf(Wh[3][3], hv3, Go);
            Gi = fmaf(Wx[0][0], hup, Gi); Gf = fmaf(Wx[1][0], hup, Gf);
            Gg = fmaf(Wx[2][0], hup, Gg); Go = fmaf(Wx[3][0], hup, Go);
            Gi = fmaf(Wx[0][1], xv1, Gi); Gf = fmaf(Wx[1][1], xv1, Gf);
            Gg = fmaf(Wx[2][1], xv1, Gg); Go = fmaf(Wx[3][1], xv1, Go);
            Gi = fmaf(Wx[0][2], xv2, Gi); Gf = fmaf(Wx[1][2], xv2, Gf);
            Gg = fmaf(Wx[2][2], xv2, Gg); Go = fmaf(Wx[3][2], xv2, Go);
            Gi = fmaf(Wx[0][3], xv3, Gi); Gf = fmaf(Wx[1][3], xv3, Gf);
            Gg = fmaf(Wx[2][3], xv3, Gg); Go = fmaf(Wx[3][3], xv3, Go);
            const float si = sigf(Gi);
            const float sf = sigf(Gf);
            const float tg = tanh_(Gg);
            const float so = sigf(Go);
            const float cn = fmaf(sf, c, si * tg);
            const float hn = so * tanh_(cn);
            const bool act = (unsigned)tc < (unsigned)S_LEN;
            c = act ? cn : c;
            h = act ? hn : h;
            // linear head (valid on L5 lanes; buffered, stored at chunk end)
            float s = h * regw;
            s += dppf<0xB1>(s);
            s += dppf<0x4E>(s);
            su[u] = s + regb;
        }
        // ---- drain head outputs for this chunk ----
        if (isOut) {
            const int base = cc * CH - (NL - 1);
#pragma unroll
            for (int u = 0; u < CH; ++u) {
                const int t = base + u;
                if (t >= 0 && t < S_LEN) out[(size_t)t * BATCH + b] = su[u];
            }
        }
        // ---- rotate prefetch buffer ----
#pragma unroll
        for (int u = 0; u < CH; ++u) xu[u] = xp[u];
    }
}

extern "C" void kernel_launch(void* const* d_in, const int* in_sizes, int n_in,
                              void* d_out, int out_size, void* d_ws, size_t ws_size,
                              hipStream_t stream) {
    const float* x     = (const float*)d_in[0];
    const float* w_ih  = (const float*)d_in[1];
    const float* w_hh  = (const float*)d_in[2];
    const float* b_ih  = (const float*)d_in[3];
    const float* b_hh  = (const float*)d_in[4];
    const float* reg_w = (const float*)d_in[5];
    const float* reg_b = (const float*)d_in[6];
    float* out = (float*)d_out;

    dim3 grid(BATCH / 2);   // 512 single-wave blocks, 2 batch elements each
    dim3 block(64);
    hipLaunchKernelGGL(lstm_wavepipe, grid, block, 0, stream, x, w_ih, w_hh,
                       b_ih, b_hh, reg_w, reg_b, out);
}